// Round 2
// baseline (294.912 us; speedup 1.0000x reference)
//
#include <hip/hip_runtime.h>
#include <hip/hip_bf16.h>

typedef unsigned short u16;
typedef __bf16 bf16x8 __attribute__((ext_vector_type(8)));
typedef float f32x4 __attribute__((ext_vector_type(4)));
typedef unsigned short u16x8 __attribute__((ext_vector_type(8)));
typedef unsigned short u16x4 __attribute__((ext_vector_type(4)));

__device__ __forceinline__ float bf2f(u16 u) {
  unsigned x = ((unsigned)u) << 16;
  return __builtin_bit_cast(float, x);
}
__device__ __forceinline__ u16 f2bf(float f) {
  unsigned u = __builtin_bit_cast(unsigned, f);
  u += 0x7fffu + ((u >> 16) & 1u);
  return (u16)(u >> 16);
}

// async global -> LDS, 16B per lane; lds base must be wave-uniform,
// HW scatters at base + lane*16.
__device__ __forceinline__ void gload16(const u16* g, u16* lds) {
  __builtin_amdgcn_global_load_lds(
      (const __attribute__((address_space(1))) void*)g,
      (__attribute__((address_space(3))) void*)lds,
      16, 0, 0);
}

// -------------------------------------------------------------------------
// C[M,N] = A[M,K] * B[N,K]^T, bf16 inputs row-major with strides lda/ldb.
// 128x128 tile, BK=32, 4 waves each computing 64x64 (4x4 MFMA 16x16x32).
// Kc = K-elements per block; blockIdx.z selects the K chunk (split-K).
// OUT_MODE: 0 = f32 store, 1 = bf16 store, 2 = f32 atomicAdd (split-K).
// -------------------------------------------------------------------------
template <int OUT_MODE>
__global__ __launch_bounds__(256) void gemm_bt(
    const u16* __restrict__ A, int lda,
    const u16* __restrict__ B, int ldb,
    void* __restrict__ C, int ldc, int Kc)
{
  __shared__ __align__(16) u16 As[128 * 32];
  __shared__ __align__(16) u16 Bs[128 * 32];

  const int m0 = blockIdx.y * 128;
  const int n0 = blockIdx.x * 128;
  const int kt0 = blockIdx.z * Kc;
  const int t = threadIdx.x;
  const int w = t >> 6, l = t & 63;
  const int sr = l >> 2;           // staging sub-row 0..15
  const int sc = (l & 3) * 8;      // staging col offset (elements)
  const int wm = (w >> 1) * 64, wn = (w & 1) * 64;
  const int fr = l & 15;           // fragment row
  const int fk = (l >> 4) * 8;     // fragment k offset

  f32x4 acc[4][4] = {};

  for (int kk = 0; kk < Kc; kk += 32) {
    const int kt = kt0 + kk;
    __syncthreads();
#pragma unroll
    for (int j = 0; j < 2; ++j) {
      const int rr = 16 * (2 * w + j);          // wave-uniform row base
      gload16(A + (size_t)(m0 + rr + sr) * lda + kt + sc, As + rr * 32);
      gload16(B + (size_t)(n0 + rr + sr) * ldb + kt + sc, Bs + rr * 32);
    }
    __syncthreads();

    bf16x8 af[4], bf[4];
#pragma unroll
    for (int i = 0; i < 4; ++i)
      af[i] = *(const bf16x8*)(As + (wm + 16 * i + fr) * 32 + fk);
#pragma unroll
    for (int j = 0; j < 4; ++j)
      bf[j] = *(const bf16x8*)(Bs + (wn + 16 * j + fr) * 32 + fk);
#pragma unroll
    for (int i = 0; i < 4; ++i)
#pragma unroll
      for (int j = 0; j < 4; ++j)
        acc[i][j] = __builtin_amdgcn_mfma_f32_16x16x32_bf16(af[i], bf[j], acc[i][j], 0, 0, 0);
  }

  // C/D layout (m89-verified): col = lane&15, row = (lane>>4)*4 + reg
  const int er = (l >> 4) * 4;
  const int ec = l & 15;
#pragma unroll
  for (int i = 0; i < 4; ++i)
#pragma unroll
    for (int j = 0; j < 4; ++j)
#pragma unroll
      for (int r = 0; r < 4; ++r) {
        const size_t idx = (size_t)(m0 + wm + 16 * i + er + r) * ldc + (n0 + wn + 16 * j + ec);
        if (OUT_MODE == 1)      ((u16*)C)[idx] = f2bf(acc[i][j][r]);
        else if (OUT_MODE == 0) ((float*)C)[idx] = acc[i][j][r];
        else                    unsafeAtomicAdd(((float*)C) + idx, acc[i][j][r]);
      }
}

// -------------------------------------------------------------------------
// zero-fill d_out (fp32), 1 float4 per thread
// -------------------------------------------------------------------------
__global__ __launch_bounds__(256) void zero_f32(float4* __restrict__ p) {
  p[blockIdx.x * 256 + threadIdx.x] = float4{0.f, 0.f, 0.f, 0.f};
}

// -------------------------------------------------------------------------
// elementwise f32 -> bf16 cast, 4 elems/thread
// -------------------------------------------------------------------------
__global__ __launch_bounds__(256) void cast_f32_bf16(const float* __restrict__ in,
                                                     u16* __restrict__ out) {
  const int i = (blockIdx.x * 256 + threadIdx.x) * 4;
  float4 f = *(const float4*)(in + i);
  u16x4 o;
  o.x = f2bf(f.x); o.y = f2bf(f.y); o.z = f2bf(f.z); o.w = f2bf(f.w);
  *(u16x4*)(out + i) = o;
}

// -------------------------------------------------------------------------
// tiled transpose: out[c*ldout + r] = cvt(in[r*ldin + c]).  block (32,32).
// grid (C/32, R/32).  T = float (cast to bf16) or u16 (copy bits).
// -------------------------------------------------------------------------
template <typename T>
__global__ __launch_bounds__(1024) void transpose_to_bf16(
    const T* __restrict__ in, int ldin, u16* __restrict__ out, int ldout)
{
  __shared__ u16 tile[32][33];
  const int c0 = blockIdx.x * 32, r0 = blockIdx.y * 32;
  const int tx = threadIdx.x, ty = threadIdx.y;
  T v = in[(size_t)(r0 + ty) * ldin + c0 + tx];
  if constexpr (__is_same(T, float)) tile[ty][tx] = f2bf(v);
  else                               tile[ty][tx] = v;
  __syncthreads();
  out[(size_t)(c0 + ty) * ldout + r0 + tx] = tile[tx][ty];
}

// -------------------------------------------------------------------------
// row softmax, in-place on bf16 S[4096][4096]; scale folded in.
// one 256-thread block per row; 16 elems/thread.
// -------------------------------------------------------------------------
__global__ __launch_bounds__(256) void softmax_rows(u16* __restrict__ S, float scale) {
  const int N = 4096;
  u16* p = S + (size_t)blockIdx.x * N;
  const int t = threadIdx.x;
  u16x8 u0 = ((const u16x8*)p)[t * 2];
  u16x8 u1 = ((const u16x8*)p)[t * 2 + 1];
  float v[16];
#pragma unroll
  for (int i = 0; i < 8; ++i) v[i] = bf2f(u0[i]) * scale;
#pragma unroll
  for (int i = 0; i < 8; ++i) v[8 + i] = bf2f(u1[i]) * scale;

  float m = -1e30f;
#pragma unroll
  for (int i = 0; i < 16; ++i) m = fmaxf(m, v[i]);
#pragma unroll
  for (int off = 32; off; off >>= 1) m = fmaxf(m, __shfl_xor(m, off));
  __shared__ float red[8];
  if ((t & 63) == 0) red[t >> 6] = m;
  __syncthreads();
  m = fmaxf(fmaxf(red[0], red[1]), fmaxf(red[2], red[3]));

  float s = 0.f;
#pragma unroll
  for (int i = 0; i < 16; ++i) { v[i] = __expf(v[i] - m); s += v[i]; }
#pragma unroll
  for (int off = 32; off; off >>= 1) s += __shfl_xor(s, off);
  if ((t & 63) == 0) red[4 + (t >> 6)] = s;
  __syncthreads();
  s = (red[4] + red[5]) + (red[6] + red[7]);
  const float inv = 1.0f / s;

  u16x8 o0, o1;
#pragma unroll
  for (int i = 0; i < 8; ++i) o0[i] = f2bf(v[i] * inv);
#pragma unroll
  for (int i = 0; i < 8; ++i) o1[i] = f2bf(v[8 + i] * inv);
  ((u16x8*)p)[t * 2] = o0;
  ((u16x8*)p)[t * 2 + 1] = o1;
}

// -------------------------------------------------------------------------
// S=4096, D_IN=1024, D_OUT=1024.  fp32 in, fp32 out.
// ws layout (bytes): Ebf 8MB | Wt 6MB | QKV 24MB | Vt 8MB | S 32MB = 78MB
// -------------------------------------------------------------------------
extern "C" void kernel_launch(void* const* d_in, const int* in_sizes, int n_in,
                              void* d_out, int out_size, void* d_ws, size_t ws_size,
                              hipStream_t stream) {
  const float* E  = (const float*)d_in[0];
  const float* Wq = (const float*)d_in[1];
  const float* Wk = (const float*)d_in[2];
  const float* Wv = (const float*)d_in[3];
  float* Out = (float*)d_out;

  char* w = (char*)d_ws;
  u16* Ebf = (u16*)(w);
  u16* Wt  = (u16*)(w + (size_t)(8u << 20));
  u16* QKV = (u16*)(w + (size_t)(14u << 20));
  u16* Vt  = (u16*)(w + (size_t)(38u << 20));
  u16* S   = (u16*)(w + (size_t)(46u << 20));

  const dim3 tb(32, 32);

  // zero d_out for the split-K atomic accumulation (graph-safe kernel)
  zero_f32<<<4096, 256, 0, stream>>>((float4*)Out);

  // stage 0: casts / weight transposes
  cast_f32_bf16<<<4096, 256, 0, stream>>>(E, Ebf);
  transpose_to_bf16<float><<<dim3(32, 32), tb, 0, stream>>>(Wq, 1024, Wt + 0 * 1024 * 1024, 1024);
  transpose_to_bf16<float><<<dim3(32, 32), tb, 0, stream>>>(Wk, 1024, Wt + 1 * 1024 * 1024, 1024);
  transpose_to_bf16<float><<<dim3(32, 32), tb, 0, stream>>>(Wv, 1024, Wt + 2 * 1024 * 1024, 1024);

  // stage 1: QKV = E @ Wt^T   [4096 x 3072], K=1024
  gemm_bt<1><<<dim3(24, 32), 256, 0, stream>>>(Ebf, 1024, Wt, 1024, QKV, 3072, 1024);

  // V^T for the PV GEMM
  transpose_to_bf16<u16><<<dim3(32, 128), tb, 0, stream>>>(QKV + 2048, 3072, Vt, 4096);

  // stage 2: S = Q @ K^T   [4096 x 4096], K=1024
  gemm_bt<1><<<dim3(32, 32), 256, 0, stream>>>(QKV, 3072, QKV + 1024, 3072, S, 4096, 1024);

  // stage 3: P = softmax(S / 32) in place
  softmax_rows<<<4096, 256, 0, stream>>>(S, 0.03125f);

  // stage 4: Out = P @ Vt^T  [4096 x 1024], K=4096 split into 4 chunks of 1024
  gemm_bt<2><<<dim3(8, 32, 4), 256, 0, stream>>>(S, 4096, Vt, 4096, Out, 1024, 1024);
}

// Round 3
// 257.953 us; speedup vs baseline: 1.1433x; 1.1433x over previous
//
#include <hip/hip_runtime.h>
#include <hip/hip_bf16.h>

typedef unsigned short u16;
typedef __bf16 bf16x8 __attribute__((ext_vector_type(8)));
typedef float f32x4 __attribute__((ext_vector_type(4)));
typedef unsigned short u16x8 __attribute__((ext_vector_type(8)));
typedef unsigned short u16x4 __attribute__((ext_vector_type(4)));

__device__ __forceinline__ float bf2f(u16 u) {
  unsigned x = ((unsigned)u) << 16;
  return __builtin_bit_cast(float, x);
}
__device__ __forceinline__ u16 f2bf(float f) {
  unsigned u = __builtin_bit_cast(unsigned, f);
  u += 0x7fffu + ((u >> 16) & 1u);
  return (u16)(u >> 16);
}

// async global -> LDS, 16B per lane; lds base is wave-uniform,
// HW scatters at base + lane*16.
__device__ __forceinline__ void gload16(const u16* g, u16* lds) {
  __builtin_amdgcn_global_load_lds(
      (const __attribute__((address_space(1))) void*)g,
      (__attribute__((address_space(3))) void*)lds,
      16, 0, 0);
}

// -------------------------------------------------------------------------
// C[M,N] = A[M,K] * B[N,K]^T, bf16 row-major, strides lda/ldb.
// 128x128 tile, BK=64, 4 waves x (64x64 per wave, 4x4 MFMA 16x16x32).
// LDS layout: row-major [128][64] u16, but each row's eight 16B chunks are
// XOR-swizzled: global chunk c of row g sits at slot c ^ (g&7).  This keeps
// the global_load_lds lane scatter contiguous (we permute the *global*
// address per lane) and makes fragment ds_read_b128 conflict-free.
// Block mapping: 1-D grid, by = (b&7) + 8*(b/(8*NX)) so all blocks sharing
// an A row-panel land on the same XCD (b%8 selects XCD round-robin).
// OUT_MODE: 0 = f32 store, 1 = bf16 store.
// -------------------------------------------------------------------------
template <int OUT_MODE, int NX>
__device__ __forceinline__ void gemm_body(
    const u16* __restrict__ A, int lda,
    const u16* __restrict__ B, int ldb,
    void* __restrict__ C, int ldc, int K)
{
  __shared__ __align__(16) u16 As[128 * 64];
  __shared__ __align__(16) u16 Bs[128 * 64];

  const int b = blockIdx.x;
  const int by = (b & 7) + 8 * (b / (8 * NX));
  const int bx = (b >> 3) % NX;
  const int m0 = by * 128, n0 = bx * 128;

  const int t = threadIdx.x;
  const int w = t >> 6, l = t & 63;
  const int srow = l >> 3;                   // 0..7 within 8-row group
  const int schunk = ((l & 7) ^ srow) * 8;   // swizzled global chunk (elems)
  const int wm = (w >> 1) * 64, wn = (w & 1) * 64;
  const int fr = l & 15;                     // fragment row
  const int q = l >> 4;                      // quarter-wave 0..3

  f32x4 acc[4][4] = {};

  for (int kt = 0; kt < K; kt += 64) {
    __syncthreads();
#pragma unroll
    for (int j = 0; j < 4; ++j) {
      const int rr = 8 * (4 * w + j);        // wave-uniform 8-row group base
      gload16(A + (size_t)(m0 + rr + srow) * lda + kt + schunk, As + rr * 64);
      gload16(B + (size_t)(n0 + rr + srow) * ldb + kt + schunk, Bs + rr * 64);
    }
    __syncthreads();

#pragma unroll
    for (int s = 0; s < 2; ++s) {            // two K=32 MFMA steps per tile
      const int j = s * 4 + q;               // global 16B chunk index
      bf16x8 af[4], bfr[4];
#pragma unroll
      for (int i = 0; i < 4; ++i) {
        const int ra = wm + 16 * i + fr;
        af[i] = *(const bf16x8*)(As + ra * 64 + (j ^ (ra & 7)) * 8);
      }
#pragma unroll
      for (int i = 0; i < 4; ++i) {
        const int rb = wn + 16 * i + fr;
        bfr[i] = *(const bf16x8*)(Bs + rb * 64 + (j ^ (rb & 7)) * 8);
      }
#pragma unroll
      for (int i = 0; i < 4; ++i)
#pragma unroll
        for (int jj = 0; jj < 4; ++jj)
          acc[i][jj] = __builtin_amdgcn_mfma_f32_16x16x32_bf16(af[i], bfr[jj], acc[i][jj], 0, 0, 0);
    }
  }

  // C/D layout (m89-verified): col = lane&15, row = (lane>>4)*4 + reg
  const int er = q * 4;
  const int ec = l & 15;
#pragma unroll
  for (int i = 0; i < 4; ++i)
#pragma unroll
    for (int jj = 0; jj < 4; ++jj)
#pragma unroll
      for (int r = 0; r < 4; ++r) {
        const size_t idx = (size_t)(m0 + wm + 16 * i + er + r) * ldc + (n0 + wn + 16 * jj + ec);
        if (OUT_MODE == 1) ((u16*)C)[idx] = f2bf(acc[i][jj][r]);
        else               ((float*)C)[idx] = acc[i][jj][r];
      }
}

// distinct names per stage so rocprof separates them
__global__ __launch_bounds__(256) void gemm_qkv(const u16* __restrict__ A,
                                                const u16* __restrict__ B,
                                                u16* __restrict__ C) {
  gemm_body<1, 24>(A, 1024, B, 1024, C, 3072, 1024);
}
__global__ __launch_bounds__(256) void gemm_score(const u16* __restrict__ QKV,
                                                  u16* __restrict__ S) {
  gemm_body<1, 32>(QKV, 3072, QKV + 1024, 3072, S, 4096, 1024);
}
__global__ __launch_bounds__(256) void gemm_pv(const u16* __restrict__ S,
                                               const u16* __restrict__ Vt,
                                               float* __restrict__ O) {
  gemm_body<0, 8>(S, 4096, Vt, 4096, O, 1024, 4096);
}

// -------------------------------------------------------------------------
// elementwise f32 -> bf16 cast, 4 elems/thread
// -------------------------------------------------------------------------
__global__ __launch_bounds__(256) void cast_f32_bf16(const float* __restrict__ in,
                                                     u16* __restrict__ out) {
  const int i = (blockIdx.x * 256 + threadIdx.x) * 4;
  float4 f = *(const float4*)(in + i);
  u16x4 o;
  o.x = f2bf(f.x); o.y = f2bf(f.y); o.z = f2bf(f.z); o.w = f2bf(f.w);
  *(u16x4*)(out + i) = o;
}

// -------------------------------------------------------------------------
// tiled transpose: out[c*ldout + r] = cvt(in[r*ldin + c]).  block (32,32).
// -------------------------------------------------------------------------
template <typename T>
__global__ __launch_bounds__(1024) void transpose_to_bf16(
    const T* __restrict__ in, int ldin, u16* __restrict__ out, int ldout)
{
  __shared__ u16 tile[32][33];
  const int c0 = blockIdx.x * 32, r0 = blockIdx.y * 32;
  const int tx = threadIdx.x, ty = threadIdx.y;
  T v = in[(size_t)(r0 + ty) * ldin + c0 + tx];
  if constexpr (__is_same(T, float)) tile[ty][tx] = f2bf(v);
  else                               tile[ty][tx] = v;
  __syncthreads();
  out[(size_t)(c0 + ty) * ldout + r0 + tx] = tile[tx][ty];
}

// -------------------------------------------------------------------------
// row softmax, in-place on bf16 S[4096][4096]; scale folded in.
// -------------------------------------------------------------------------
__global__ __launch_bounds__(256) void softmax_rows(u16* __restrict__ S, float scale) {
  const int N = 4096;
  u16* p = S + (size_t)blockIdx.x * N;
  const int t = threadIdx.x;
  u16x8 u0 = ((const u16x8*)p)[t * 2];
  u16x8 u1 = ((const u16x8*)p)[t * 2 + 1];
  float v[16];
#pragma unroll
  for (int i = 0; i < 8; ++i) v[i] = bf2f(u0[i]) * scale;
#pragma unroll
  for (int i = 0; i < 8; ++i) v[8 + i] = bf2f(u1[i]) * scale;

  float m = -1e30f;
#pragma unroll
  for (int i = 0; i < 16; ++i) m = fmaxf(m, v[i]);
#pragma unroll
  for (int off = 32; off; off >>= 1) m = fmaxf(m, __shfl_xor(m, off));
  __shared__ float red[8];
  if ((t & 63) == 0) red[t >> 6] = m;
  __syncthreads();
  m = fmaxf(fmaxf(red[0], red[1]), fmaxf(red[2], red[3]));

  float s = 0.f;
#pragma unroll
  for (int i = 0; i < 16; ++i) { v[i] = __expf(v[i] - m); s += v[i]; }
#pragma unroll
  for (int off = 32; off; off >>= 1) s += __shfl_xor(s, off);
  if ((t & 63) == 0) red[4 + (t >> 6)] = s;
  __syncthreads();
  s = (red[4] + red[5]) + (red[6] + red[7]);
  const float inv = 1.0f / s;

  u16x8 o0, o1;
#pragma unroll
  for (int i = 0; i < 8; ++i) o0[i] = f2bf(v[i] * inv);
#pragma unroll
  for (int i = 0; i < 8; ++i) o1[i] = f2bf(v[8 + i] * inv);
  ((u16x8*)p)[t * 2] = o0;
  ((u16x8*)p)[t * 2 + 1] = o1;
}

// -------------------------------------------------------------------------
// S=4096, D_IN=1024, D_OUT=1024.  fp32 in, fp32 out.
// ws layout (bytes): Ebf 8MB | Wt 6MB | QKV 24MB | Vt 8MB | S 32MB = 78MB
// -------------------------------------------------------------------------
extern "C" void kernel_launch(void* const* d_in, const int* in_sizes, int n_in,
                              void* d_out, int out_size, void* d_ws, size_t ws_size,
                              hipStream_t stream) {
  const float* E  = (const float*)d_in[0];
  const float* Wq = (const float*)d_in[1];
  const float* Wk = (const float*)d_in[2];
  const float* Wv = (const float*)d_in[3];
  float* Out = (float*)d_out;

  char* w = (char*)d_ws;
  u16* Ebf = (u16*)(w);
  u16* Wt  = (u16*)(w + (size_t)(8u << 20));
  u16* QKV = (u16*)(w + (size_t)(14u << 20));
  u16* Vt  = (u16*)(w + (size_t)(38u << 20));
  u16* S   = (u16*)(w + (size_t)(46u << 20));

  const dim3 tb(32, 32);

  // stage 0: casts / weight transposes
  cast_f32_bf16<<<4096, 256, 0, stream>>>(E, Ebf);
  transpose_to_bf16<float><<<dim3(32, 32), tb, 0, stream>>>(Wq, 1024, Wt + 0 * 1024 * 1024, 1024);
  transpose_to_bf16<float><<<dim3(32, 32), tb, 0, stream>>>(Wk, 1024, Wt + 1 * 1024 * 1024, 1024);
  transpose_to_bf16<float><<<dim3(32, 32), tb, 0, stream>>>(Wv, 1024, Wt + 2 * 1024 * 1024, 1024);

  // stage 1: QKV = E @ Wt^T   [4096 x 3072], K=1024
  gemm_qkv<<<768, 256, 0, stream>>>(Ebf, Wt, QKV);

  // V^T for the PV GEMM
  transpose_to_bf16<u16><<<dim3(32, 128), tb, 0, stream>>>(QKV + 2048, 3072, Vt, 4096);

  // stage 2: S = Q @ K^T   [4096 x 4096], K=1024
  gemm_score<<<1024, 256, 0, stream>>>(QKV, S);

  // stage 3: P = softmax(S / 32) in place
  softmax_rows<<<4096, 256, 0, stream>>>(S, 0.03125f);

  // stage 4: Out = P @ Vt^T  [4096 x 1024], K=4096
  gemm_pv<<<256, 256, 0, stream>>>(S, Vt, Out);
}